// Round 1
// baseline (1407.089 us; speedup 1.0000x reference)
//
#include <hip/hip_runtime.h>
#include <math.h>

#define S_LEN  2048
#define BATCH  2
#define DMODEL 1024
#define NHEAD  16
#define DHEAD  64
#define WIN    256
#define MROWS  (S_LEN * BATCH)   // 4096

// ---------------------------------------------------------------------------
// GEMM: C = A(4096x1024) @ B(1024x1024) + bias, epilogue modes:
//  mode 0: plain row-major store (output projection -> d_out)
//  mode 1: q: scale by 0.125*exp(-beta[h]), scatter to (z, s, dh) layout
//  mode 2: k/v: scatter to (z, s, dh) layout
// Each 64-wide column tile is exactly one head (h = colBase/64).
// ---------------------------------------------------------------------------
__global__ __launch_bounds__(256)
void gemm_ep(const float* __restrict__ A, const float* __restrict__ B,
             const float* __restrict__ bias, const float* __restrict__ beta,
             float* __restrict__ C, int mode)
{
    __shared__ float As[16][65];   // K-major, padded
    __shared__ float Bs[16][65];

    const int t  = threadIdx.x;
    const int tx = t & 15, ty = t >> 4;
    const int rowBase = blockIdx.y * 64;
    const int colBase = blockIdx.x * 64;

    float acc[4][4] = {};

    for (int kb = 0; kb < DMODEL; kb += 16) {
        // A tile: 64 rows x 16 k, float4 per thread (4 threads/row)
        {
            const int r  = t >> 2;
            const int c4 = (t & 3) << 2;
            float4 a4 = *(const float4*)(A + (size_t)(rowBase + r) * DMODEL + kb + c4);
            As[c4 + 0][r] = a4.x; As[c4 + 1][r] = a4.y;
            As[c4 + 2][r] = a4.z; As[c4 + 3][r] = a4.w;
            // B tile: 16 k-rows x 64 cols, float4 per thread (16 threads/row)
            const int br  = t >> 4;
            const int bc4 = (t & 15) << 2;
            float4 b4 = *(const float4*)(B + (size_t)(kb + br) * DMODEL + colBase + bc4);
            Bs[br][bc4 + 0] = b4.x; Bs[br][bc4 + 1] = b4.y;
            Bs[br][bc4 + 2] = b4.z; Bs[br][bc4 + 3] = b4.w;
        }
        __syncthreads();
#pragma unroll
        for (int kk = 0; kk < 16; ++kk) {
            float a[4], b[4];
#pragma unroll
            for (int u = 0; u < 4; ++u) a[u] = As[kk][ty + 16 * u];
#pragma unroll
            for (int v = 0; v < 4; ++v) b[v] = Bs[kk][tx + 16 * v];
#pragma unroll
            for (int u = 0; u < 4; ++u)
#pragma unroll
                for (int v = 0; v < 4; ++v)
                    acc[u][v] = fmaf(a[u], b[v], acc[u][v]);
        }
        __syncthreads();
    }

    if (mode == 0) {
#pragma unroll
        for (int u = 0; u < 4; ++u) {
            const int r = rowBase + ty + 16 * u;
#pragma unroll
            for (int v = 0; v < 4; ++v) {
                const int c = colBase + tx + 16 * v;
                C[(size_t)r * DMODEL + c] = acc[u][v] + bias[c];
            }
        }
    } else {
        const int h = colBase >> 6;                       // head for this tile
        const float scale = (mode == 1) ? 0.125f * __expf(-beta[h]) : 1.0f;
#pragma unroll
        for (int u = 0; u < 4; ++u) {
            const int r  = rowBase + ty + 16 * u;
            const int s  = r >> 1;                        // row = s*B + b
            const int bb = r & 1;
            const int z  = bb * NHEAD + h;
#pragma unroll
            for (int v = 0; v < 4; ++v) {
                const int c  = colBase + tx + 16 * v;
                const int dh = c & 63;
                C[((size_t)z * S_LEN + s) * DHEAD + dh] = (acc[u][v] + bias[c]) * scale;
            }
        }
    }
}

// ---------------------------------------------------------------------------
// Windowed causal attention with sink. One wave per (z, query row i).
// q/k/v in (z, s, dh) layout. Output ao in (s*B+b, h*64+dh) row-major so the
// final projection is a plain GEMM.
// ---------------------------------------------------------------------------
__global__ __launch_bounds__(256)
void attn_win(const float* __restrict__ q, const float* __restrict__ k,
              const float* __restrict__ v, float* __restrict__ ao)
{
    const int lane = threadIdx.x & 63;
    const int w    = blockIdx.x * 4 + (threadIdx.x >> 6);
    const int z    = w >> 11;          // / 2048
    const int i    = w & 2047;
    int wstart = i - (WIN - 1);
    if (wstart < 0) wstart = 0;

    // q row into registers (wave-uniform address -> broadcast loads)
    const float4* qrow = (const float4*)(q + ((size_t)z * S_LEN + i) * DHEAD);
    float4 qr[16];
#pragma unroll
    for (int d = 0; d < 16; ++d) qr[d] = qrow[d];

    // --- scores: lane owns keys jj = wstart + t4*64 + lane ---
    float p[4];
    float m = -INFINITY;
#pragma unroll
    for (int t4 = 0; t4 < 4; ++t4) {
        const int jj = wstart + t4 * 64 + lane;          // always < S_LEN (safe read)
        const bool valid = (jj <= i);
        const float4* krow = (const float4*)(k + ((size_t)z * S_LEN + jj) * DHEAD);
        float acc = 0.f;
#pragma unroll
        for (int d = 0; d < 16; ++d) {
            float4 k4 = krow[d];
            acc = fmaf(qr[d].x, k4.x, acc);
            acc = fmaf(qr[d].y, k4.y, acc);
            acc = fmaf(qr[d].z, k4.z, acc);
            acc = fmaf(qr[d].w, k4.w, acc);
        }
        p[t4] = valid ? acc : -INFINITY;
        m = fmaxf(m, p[t4]);
    }
#pragma unroll
    for (int off = 32; off >= 1; off >>= 1)
        m = fmaxf(m, __shfl_xor(m, off, 64));
    m = fmaxf(m, 0.0f);                                   // sink logit = 0

    float lsum = 0.f;
#pragma unroll
    for (int t4 = 0; t4 < 4; ++t4) {
        p[t4] = (p[t4] == -INFINITY) ? 0.f : __expf(p[t4] - m);
        lsum += p[t4];
    }
#pragma unroll
    for (int off = 32; off >= 1; off >>= 1)
        lsum += __shfl_xor(lsum, off, 64);
    const float rden = 1.f / (lsum + __expf(-m));         // sink in denominator
#pragma unroll
    for (int t4 = 0; t4 < 4; ++t4) p[t4] *= rden;

    // --- PV: lane = output dim; broadcast p via readlane, coalesced v ---
    float out = 0.f;
#pragma unroll
    for (int t4 = 0; t4 < 4; ++t4) {
        const float* vt = v + ((size_t)z * S_LEN + wstart + t4 * 64) * DHEAD + lane;
#pragma unroll
        for (int jl = 0; jl < 64; ++jl) {
            const float a = __shfl(p[t4], jl, 64);
            out = fmaf(a, vt[(size_t)jl * DHEAD], out);
        }
    }

    const int bb = z >> 4, h = z & 15;
    ao[(size_t)(i * BATCH + bb) * DMODEL + h * DHEAD + lane] = out;
}

// ---------------------------------------------------------------------------
extern "C" void kernel_launch(void* const* d_in, const int* in_sizes, int n_in,
                              void* d_out, int out_size, void* d_ws, size_t ws_size,
                              hipStream_t stream)
{
    const float* x    = (const float*)d_in[0];
    const float* beta = (const float*)d_in[1];
    const float* Wq   = (const float*)d_in[2];
    const float* bq   = (const float*)d_in[3];
    const float* Wk   = (const float*)d_in[4];
    const float* bk   = (const float*)d_in[5];
    const float* Wv   = (const float*)d_in[6];
    const float* bv   = (const float*)d_in[7];
    const float* Wo   = (const float*)d_in[8];
    const float* bo   = (const float*)d_in[9];
    float* out = (float*)d_out;

    // workspace: q, k, v (z,s,dh) + ao (row-major 4096x1024) = 64 MB fp32
    float* w  = (float*)d_ws;
    const size_t seg = (size_t)MROWS * DMODEL;            // 4M floats
    float* qb = w;
    float* kb = w + seg;
    float* vb = w + 2 * seg;
    float* ab = w + 3 * seg;

    dim3 gg(DMODEL / 64, MROWS / 64);
    gemm_ep<<<gg, 256, 0, stream>>>(x, Wq, bq, beta, qb, 1);
    gemm_ep<<<gg, 256, 0, stream>>>(x, Wk, bk, beta, kb, 2);
    gemm_ep<<<gg, 256, 0, stream>>>(x, Wv, bv, beta, vb, 2);

    attn_win<<<(BATCH * NHEAD * S_LEN) / 4, 256, 0, stream>>>(qb, kb, vb, ab);

    gemm_ep<<<gg, 256, 0, stream>>>(ab, Wo, bo, beta, out, 0);
}

// Round 2
// 769.787 us; speedup vs baseline: 1.8279x; 1.8279x over previous
//
#include <hip/hip_runtime.h>
#include <math.h>

#define S_LEN  2048
#define BATCH  2
#define DMODEL 1024
#define NHEAD  16
#define DHEAD  64
#define WIN    256
#define MROWS  (S_LEN * BATCH)   // 4096

#define TQ   64     // queries per block (attention)
#define KC   64     // keys per chunk
#define PAD  68     // LDS row pad: 16B-aligned rows, bank stride 4

// ---------------------------------------------------------------------------
// GEMM: C = A(4096x1024) @ B(1024x1024) + bias, epilogue modes:
//  mode 0: plain row-major store (output projection -> d_out)
//  mode 1: q: scale by 0.125*exp(-beta[h]), scatter to (z, s, dh) layout
//  mode 2: k/v: scatter to (z, s, dh) layout
// ---------------------------------------------------------------------------
__global__ __launch_bounds__(256)
void gemm_ep(const float* __restrict__ A, const float* __restrict__ B,
             const float* __restrict__ bias, const float* __restrict__ beta,
             float* __restrict__ C, int mode)
{
    __shared__ float As[16][65];   // K-major, padded
    __shared__ float Bs[16][65];

    const int t  = threadIdx.x;
    const int tx = t & 15, ty = t >> 4;
    const int rowBase = blockIdx.y * 64;
    const int colBase = blockIdx.x * 64;

    float acc[4][4] = {};

    for (int kb = 0; kb < DMODEL; kb += 16) {
        {
            const int r  = t >> 2;
            const int c4 = (t & 3) << 2;
            float4 a4 = *(const float4*)(A + (size_t)(rowBase + r) * DMODEL + kb + c4);
            As[c4 + 0][r] = a4.x; As[c4 + 1][r] = a4.y;
            As[c4 + 2][r] = a4.z; As[c4 + 3][r] = a4.w;
            const int br  = t >> 4;
            const int bc4 = (t & 15) << 2;
            float4 b4 = *(const float4*)(B + (size_t)(kb + br) * DMODEL + colBase + bc4);
            Bs[br][bc4 + 0] = b4.x; Bs[br][bc4 + 1] = b4.y;
            Bs[br][bc4 + 2] = b4.z; Bs[br][bc4 + 3] = b4.w;
        }
        __syncthreads();
#pragma unroll
        for (int kk = 0; kk < 16; ++kk) {
            float a[4], b[4];
#pragma unroll
            for (int u = 0; u < 4; ++u) a[u] = As[kk][ty + 16 * u];
#pragma unroll
            for (int v = 0; v < 4; ++v) b[v] = Bs[kk][tx + 16 * v];
#pragma unroll
            for (int u = 0; u < 4; ++u)
#pragma unroll
                for (int v = 0; v < 4; ++v)
                    acc[u][v] = fmaf(a[u], b[v], acc[u][v]);
        }
        __syncthreads();
    }

    if (mode == 0) {
#pragma unroll
        for (int u = 0; u < 4; ++u) {
            const int r = rowBase + ty + 16 * u;
#pragma unroll
            for (int v = 0; v < 4; ++v) {
                const int c = colBase + tx + 16 * v;
                C[(size_t)r * DMODEL + c] = acc[u][v] + bias[c];
            }
        }
    } else {
        const int h = colBase >> 6;
        const float scale = (mode == 1) ? 0.125f * __expf(-beta[h]) : 1.0f;
#pragma unroll
        for (int u = 0; u < 4; ++u) {
            const int r  = rowBase + ty + 16 * u;
            const int s  = r >> 1;
            const int bb = r & 1;
            const int z  = bb * NHEAD + h;
#pragma unroll
            for (int v = 0; v < 4; ++v) {
                const int c  = colBase + tx + 16 * v;
                const int dh = c & 63;
                C[((size_t)z * S_LEN + s) * DHEAD + dh] = (acc[u][v] + bias[c]) * scale;
            }
        }
    }
}

// ---------------------------------------------------------------------------
// Tiled windowed attention with sink, flash-style online softmax.
// Block = 256 threads handles TQ=64 query rows of one z.
// Key window union for the tile: [q0-256, q0+63] in 5 chunks of 64.
// Online softmax init m=0, l=1 absorbs the zero-logit sink column exactly.
// Microtile: thread (tx,ty) owns rows ty*4+u, cols tx*4+v  -> all LDS
// traffic is b128. Row-reduction = shuffle over the 16 lanes sharing ty.
// ---------------------------------------------------------------------------
__global__ __launch_bounds__(256)
void attn_tile(const float* __restrict__ q, const float* __restrict__ k,
               const float* __restrict__ v, float* __restrict__ ao)
{
    __shared__ float Qs[64][PAD];  // d-major: Qs[d][i]
    __shared__ float Ks[64][PAD];  // d-major: Ks[d][j]
    __shared__ float Vs[64][PAD];  // k-major: Vs[kk][dh]
    __shared__ float Ps[64][PAD];  // query-major: Ps[i][j]

    const int t  = threadIdx.x;
    const int tx = t & 15, ty = t >> 4;
    const int z  = blockIdx.y;
    const int q0 = blockIdx.x * TQ;
    const size_t zbase = (size_t)z * S_LEN * DHEAD;

    // ---- stage Q transposed (coalesced row loads, column writes) ----
#pragma unroll
    for (int p = 0; p < 4; ++p) {
        const int i  = p * 16 + ty;
        const int d4 = tx << 2;
        float4 a4 = *(const float4*)(q + zbase + (size_t)(q0 + i) * DHEAD + d4);
        Qs[d4 + 0][i] = a4.x; Qs[d4 + 1][i] = a4.y;
        Qs[d4 + 2][i] = a4.z; Qs[d4 + 3][i] = a4.w;
    }

    float o[4][4] = {};
    float mr[4], lr[4];
#pragma unroll
    for (int u = 0; u < 4; ++u) { mr[u] = 0.f; lr[u] = 1.f; }  // sink preloaded

    for (int c = 0; c < 5; ++c) {
        const int kb = q0 - 4 * KC + c * KC;   // chunk key base
        if (kb <= -KC) continue;               // fully outside valid range
        __syncthreads();                       // prev chunk's reads done

        // ---- stage K (transposed) and V (row-major) ----
#pragma unroll
        for (int p = 0; p < 4; ++p) {
            const int j  = p * 16 + ty;
            const int d4 = tx << 2;
            int jg = kb + j; if (jg < 0) jg = 0;   // clamped; masked below
            float4 k4 = *(const float4*)(k + zbase + (size_t)jg * DHEAD + d4);
            Ks[d4 + 0][j] = k4.x; Ks[d4 + 1][j] = k4.y;
            Ks[d4 + 2][j] = k4.z; Ks[d4 + 3][j] = k4.w;
            float4 v4 = *(const float4*)(v + zbase + (size_t)jg * DHEAD + d4);
            *(float4*)&Vs[j][d4] = v4;
        }
        __syncthreads();

        // ---- S = Q K^T (64x64 in registers, 4x4 per thread) ----
        float s[4][4] = {};
#pragma unroll
        for (int d = 0; d < 64; ++d) {
            float4 a4 = *(const float4*)&Qs[d][ty * 4];
            float4 b4 = *(const float4*)&Ks[d][tx * 4];
            const float a[4] = {a4.x, a4.y, a4.z, a4.w};
            const float b[4] = {b4.x, b4.y, b4.z, b4.w};
#pragma unroll
            for (int u = 0; u < 4; ++u)
#pragma unroll
                for (int vv = 0; vv < 4; ++vv)
                    s[u][vv] = fmaf(a[u], b[vv], s[u][vv]);
        }

        // ---- mask + online softmax update, P -> LDS ----
#pragma unroll
        for (int u = 0; u < 4; ++u) {
            const int ig = q0 + ty * 4 + u;
            float smax = -INFINITY;
#pragma unroll
            for (int vv = 0; vv < 4; ++vv) {
                const int jg = kb + tx * 4 + vv;
                const bool valid = (jg >= 0) & (jg <= ig) & (jg >= ig - (WIN - 1));
                if (!valid) s[u][vv] = -INFINITY;
                smax = fmaxf(smax, s[u][vv]);
            }
#pragma unroll
            for (int off = 1; off < 16; off <<= 1)
                smax = fmaxf(smax, __shfl_xor(smax, off, 64));
            const float mnew  = fmaxf(mr[u], smax);
            const float alpha = __expf(mr[u] - mnew);
            float rsum = 0.f;
#pragma unroll
            for (int vv = 0; vv < 4; ++vv) {
                const float pp = (s[u][vv] == -INFINITY) ? 0.f
                                                         : __expf(s[u][vv] - mnew);
                s[u][vv] = pp;
                rsum += pp;
            }
#pragma unroll
            for (int off = 1; off < 16; off <<= 1)
                rsum += __shfl_xor(rsum, off, 64);
            lr[u] = lr[u] * alpha + rsum;
            mr[u] = mnew;
#pragma unroll
            for (int vv = 0; vv < 4; ++vv) o[u][vv] *= alpha;
            *(float4*)&Ps[ty * 4 + u][tx * 4] =
                make_float4(s[u][0], s[u][1], s[u][2], s[u][3]);
        }
        __syncthreads();

        // ---- O += P V ----
#pragma unroll
        for (int kk4 = 0; kk4 < 64; kk4 += 4) {
            float a[4][4];
#pragma unroll
            for (int u = 0; u < 4; ++u)
                *(float4*)a[u] = *(const float4*)&Ps[ty * 4 + u][kk4];
#pragma unroll
            for (int e = 0; e < 4; ++e) {
                float4 b4 = *(const float4*)&Vs[kk4 + e][tx * 4];
                const float b[4] = {b4.x, b4.y, b4.z, b4.w};
#pragma unroll
                for (int u = 0; u < 4; ++u)
#pragma unroll
                    for (int vv = 0; vv < 4; ++vv)
                        o[u][vv] = fmaf(a[u][e], b[vv], o[u][vv]);
            }
        }
    }

    // ---- epilogue: normalize, store to (s*B+b, h*64+dh) row-major ----
    const int bb = z >> 4, h = z & 15;
#pragma unroll
    for (int u = 0; u < 4; ++u) {
        const int ig = q0 + ty * 4 + u;
        const float inv = 1.f / lr[u];
        float4 r = make_float4(o[u][0] * inv, o[u][1] * inv,
                               o[u][2] * inv, o[u][3] * inv);
        *(float4*)(ao + (size_t)(ig * BATCH + bb) * DMODEL + h * DHEAD + tx * 4) = r;
    }
}

// ---------------------------------------------------------------------------
extern "C" void kernel_launch(void* const* d_in, const int* in_sizes, int n_in,
                              void* d_out, int out_size, void* d_ws, size_t ws_size,
                              hipStream_t stream)
{
    const float* x    = (const float*)d_in[0];
    const float* beta = (const float*)d_in[1];
    const float* Wq   = (const float*)d_in[2];
    const float* bq   = (const float*)d_in[3];
    const float* Wk   = (const float*)d_in[4];
    const float* bk   = (const float*)d_in[5];
    const float* Wv   = (const float*)d_in[6];
    const float* bv   = (const float*)d_in[7];
    const float* Wo   = (const float*)d_in[8];
    const float* bo   = (const float*)d_in[9];
    float* out = (float*)d_out;

    float* w  = (float*)d_ws;
    const size_t seg = (size_t)MROWS * DMODEL;            // 4M floats
    float* qb = w;
    float* kb = w + seg;
    float* vb = w + 2 * seg;
    float* ab = w + 3 * seg;

    dim3 gg(DMODEL / 64, MROWS / 64);
    gemm_ep<<<gg, 256, 0, stream>>>(x, Wq, bq, beta, qb, 1);
    gemm_ep<<<gg, 256, 0, stream>>>(x, Wk, bk, beta, kb, 2);
    gemm_ep<<<gg, 256, 0, stream>>>(x, Wv, bv, beta, vb, 2);

    attn_tile<<<dim3(S_LEN / TQ, BATCH * NHEAD), 256, 0, stream>>>(qb, kb, vb, ab);

    gemm_ep<<<gg, 256, 0, stream>>>(ab, Wo, bo, beta, out, 0);
}

// Round 3
// 307.903 us; speedup vs baseline: 4.5699x; 2.5001x over previous
//
#include <hip/hip_runtime.h>
#include <math.h>

#define S_LEN  2048
#define BATCH  2
#define DM     1024
#define NHEAD  16
#define DHEAD  64
#define WIN    256
#define MROWS  4096

#define TQ   64
#define KC   64
#define PAD  68

typedef __attribute__((ext_vector_type(8))) short bf16x8;
typedef __attribute__((ext_vector_type(4))) float f32x4;

__device__ __forceinline__ float b2f(unsigned short u) {
    union { unsigned int i; float f; } x; x.i = ((unsigned int)u) << 16; return x.f;
}
__device__ __forceinline__ unsigned short f2b(float f) {   // RNE
    unsigned int u = __float_as_uint(f);
    return (unsigned short)((u + 0x7fffu + ((u >> 16) & 1u)) >> 16);
}
__device__ __forceinline__ void gld16(const void* g, void* l) {
    __builtin_amdgcn_global_load_lds(
        (const __attribute__((address_space(1))) void*)g,
        (__attribute__((address_space(3))) void*)l, 16, 0, 0);
}

// ---------------------------------------------------------------------------
// fp32 -> bf16 convert (x): 4M elems, 4/thread
// ---------------------------------------------------------------------------
__global__ __launch_bounds__(256)
void cvtx(const float* __restrict__ x, unsigned short* __restrict__ xb)
{
    const int i = (blockIdx.x * 256 + threadIdx.x) * 4;
    float4 f = *(const float4*)(x + i);
    ushort4 o; o.x = f2b(f.x); o.y = f2b(f.y); o.z = f2b(f.z); o.w = f2b(f.w);
    *(ushort4*)(xb + i) = o;
}

// ---------------------------------------------------------------------------
// W (K x N fp32) -> W^T (N x K bf16), 32x32 LDS tiles
// ---------------------------------------------------------------------------
__global__ __launch_bounds__(256)
void twcvt(const float* __restrict__ W, unsigned short* __restrict__ WT)
{
    __shared__ float t32[32][33];
    const int bx = blockIdx.x * 32;   // col base (n)
    const int by = blockIdx.y * 32;   // row base (k)
    const int c  = threadIdx.x & 31;
    const int r0 = threadIdx.x >> 5;  // 0..7
#pragma unroll
    for (int p = 0; p < 4; ++p)
        t32[r0 + 8 * p][c] = W[(size_t)(by + r0 + 8 * p) * DM + bx + c];
    __syncthreads();
#pragma unroll
    for (int p = 0; p < 4; ++p)
        WT[(size_t)(bx + r0 + 8 * p) * DM + by + c] = f2b(t32[c][r0 + 8 * p]);
}

// ---------------------------------------------------------------------------
// bf16 MFMA GEMM: C(4096xDM) = A(4096xDM) @ BT^T, + bias epilogues.
// A row-major bf16, BT = W^T row-major (N x K) bf16.
// Tile 128x64, BK=32, 256 thr = 4 waves (2x2 of 64x32).
// mode 0: fp32 +bias -> Cf ; mode 1: q scale+scatter bf16 ; mode 2: scatter.
// ---------------------------------------------------------------------------
__global__ __launch_bounds__(256, 2)
void gemm_mfma(const unsigned short* __restrict__ A,
               const unsigned short* __restrict__ BT,
               const float* __restrict__ bias,
               const float* __restrict__ beta,
               float* __restrict__ Cf,
               unsigned short* __restrict__ Cb,
               int mode)
{
    __shared__ unsigned short As[128 * 32];  // 8 KB, row-major 128x32
    __shared__ unsigned short Bs[64 * 32];   // 4 KB, row-major 64x32 (rows = out cols)

    const int t  = threadIdx.x;
    const int wv = t >> 6, ln = t & 63;
    const int rowBase = blockIdx.y * 128;
    const int colBase = blockIdx.x * 64;

    const int lr = ln >> 2;           // staging: row within 16-row chunk
    const int lk = (ln & 3) * 8;      // staging: k element offset
    const int m16 = ln & 15;          // frag row/col
    const int q8  = (ln >> 4) * 8;    // frag k offset
    const int wr = wv >> 1, wc = wv & 1;

    const unsigned short* ga = A  + (size_t)(rowBase + wv * 32 + lr) * DM + lk;
    const unsigned short* gb = BT + (size_t)(colBase + wv * 16 + lr) * DM + lk;
    unsigned short* la0 = As + wv * 1024;          // bytes 2048*wv
    unsigned short* la1 = la0 + 512;
    unsigned short* lb  = Bs + wv * 512;

    f32x4 acc[4][2];
#pragma unroll
    for (int u = 0; u < 4; ++u)
#pragma unroll
        for (int v = 0; v < 2; ++v)
            acc[u][v] = (f32x4){0.f, 0.f, 0.f, 0.f};

    for (int kb = 0; kb < DM; kb += 32) {
        gld16(ga + kb, la0);
        gld16(ga + 16 * DM + kb, la1);
        gld16(gb + kb, lb);
        __syncthreads();

        bf16x8 af[4], bfr[2];
#pragma unroll
        for (int u = 0; u < 4; ++u)
            af[u] = *(const bf16x8*)&As[(wr * 64 + u * 16 + m16) * 32 + q8];
#pragma unroll
        for (int v = 0; v < 2; ++v)
            bfr[v] = *(const bf16x8*)&Bs[(wc * 32 + v * 16 + m16) * 32 + q8];
#pragma unroll
        for (int u = 0; u < 4; ++u)
#pragma unroll
            for (int v = 0; v < 2; ++v)
                acc[u][v] = __builtin_amdgcn_mfma_f32_16x16x32_bf16(
                    af[u], bfr[v], acc[u][v], 0, 0, 0);
        __syncthreads();
    }

    const int roww = rowBase + wr * 64;
    const int colw = colBase + wc * 32;
    const int q4 = (ln >> 4) * 4;
    if (mode == 0) {
#pragma unroll
        for (int u = 0; u < 4; ++u)
#pragma unroll
            for (int v = 0; v < 2; ++v) {
                const int col = colw + v * 16 + m16;
                const float bi = bias[col];
#pragma unroll
                for (int r = 0; r < 4; ++r) {
                    const int row = roww + u * 16 + q4 + r;
                    Cf[(size_t)row * DM + col] = acc[u][v][r] + bi;
                }
            }
    } else {
        const int h = colBase >> 6;
        const float scale = (mode == 1) ? 0.125f * __expf(-beta[h]) : 1.0f;
#pragma unroll
        for (int u = 0; u < 4; ++u)
#pragma unroll
            for (int v = 0; v < 2; ++v) {
                const int col = colw + v * 16 + m16;
                const int dh  = col & 63;
                const float bi = bias[col];
#pragma unroll
                for (int r = 0; r < 4; ++r) {
                    const int row = roww + u * 16 + q4 + r;
                    const int s = row >> 1, bb = row & 1;
                    const int z = bb * NHEAD + h;
                    Cb[((size_t)z * S_LEN + s) * DHEAD + dh] =
                        f2b((acc[u][v][r] + bi) * scale);
                }
            }
    }
}

// ---------------------------------------------------------------------------
// Tiled windowed attention with sink (bf16 q/k/v in, bf16 out).
// Block = 256 threads, TQ=64 query rows of one z, 5 key chunks of 64.
// Online softmax m=0, l=1 absorbs the sink. fp32 math throughout.
// ---------------------------------------------------------------------------
__global__ __launch_bounds__(256)
void attn_tile(const unsigned short* __restrict__ q,
               const unsigned short* __restrict__ k,
               const unsigned short* __restrict__ v,
               unsigned short* __restrict__ ao)
{
    __shared__ float Qs[64][PAD];  // d-major
    __shared__ float Ks[64][PAD];  // d-major
    __shared__ float Vs[64][PAD];  // k-major
    __shared__ float Ps[64][PAD];  // query-major

    const int t  = threadIdx.x;
    const int tx = t & 15, ty = t >> 4;
    const int z  = blockIdx.y;
    const int q0 = blockIdx.x * TQ;
    const size_t zbase = (size_t)z * S_LEN * DHEAD;

#pragma unroll
    for (int p = 0; p < 4; ++p) {
        const int i  = p * 16 + ty;
        const int d4 = tx << 2;
        ushort4 a4 = *(const ushort4*)(q + zbase + (size_t)(q0 + i) * DHEAD + d4);
        Qs[d4 + 0][i] = b2f(a4.x); Qs[d4 + 1][i] = b2f(a4.y);
        Qs[d4 + 2][i] = b2f(a4.z); Qs[d4 + 3][i] = b2f(a4.w);
    }

    float o[4][4] = {};
    float mr[4], lr[4];
#pragma unroll
    for (int u = 0; u < 4; ++u) { mr[u] = 0.f; lr[u] = 1.f; }

    for (int c = 0; c < 5; ++c) {
        const int kb = q0 - 4 * KC + c * KC;
        if (kb <= -KC) continue;
        __syncthreads();

#pragma unroll
        for (int p = 0; p < 4; ++p) {
            const int j  = p * 16 + ty;
            const int d4 = tx << 2;
            int jg = kb + j; if (jg < 0) jg = 0;
            ushort4 k4 = *(const ushort4*)(k + zbase + (size_t)jg * DHEAD + d4);
            Ks[d4 + 0][j] = b2f(k4.x); Ks[d4 + 1][j] = b2f(k4.y);
            Ks[d4 + 2][j] = b2f(k4.z); Ks[d4 + 3][j] = b2f(k4.w);
            ushort4 v4 = *(const ushort4*)(v + zbase + (size_t)jg * DHEAD + d4);
            Vs[j][d4 + 0] = b2f(v4.x); Vs[j][d4 + 1] = b2f(v4.y);
            Vs[j][d4 + 2] = b2f(v4.z); Vs[j][d4 + 3] = b2f(v4.w);
        }
        __syncthreads();

        float s[4][4] = {};
#pragma unroll
        for (int d = 0; d < 64; ++d) {
            float4 a4 = *(const float4*)&Qs[d][ty * 4];
            float4 b4 = *(const float4*)&Ks[d][tx * 4];
            const float a[4] = {a4.x, a4.y, a4.z, a4.w};
            const float b[4] = {b4.x, b4.y, b4.z, b4.w};
#pragma unroll
            for (int u = 0; u < 4; ++u)
#pragma unroll
                for (int vv = 0; vv < 4; ++vv)
                    s[u][vv] = fmaf(a[u], b[vv], s[u][vv]);
        }

#pragma unroll
        for (int u = 0; u < 4; ++u) {
            const int ig = q0 + ty * 4 + u;
            float smax = -INFINITY;
#pragma unroll
            for (int vv = 0; vv < 4; ++vv) {
                const int jg = kb + tx * 4 + vv;
                const bool valid = (jg >= 0) & (jg <= ig) & (jg >= ig - (WIN - 1));
                if (!valid) s[u][vv] = -INFINITY;
                smax = fmaxf(smax, s[u][vv]);
            }
#pragma unroll
            for (int off = 1; off < 16; off <<= 1)
                smax = fmaxf(smax, __shfl_xor(smax, off, 64));
            const float mnew  = fmaxf(mr[u], smax);
            const float alpha = __expf(mr[u] - mnew);
            float rsum = 0.f;
#pragma unroll
            for (int vv = 0; vv < 4; ++vv) {
                const float pp = (s[u][vv] == -INFINITY) ? 0.f
                                                         : __expf(s[u][vv] - mnew);
                s[u][vv] = pp;
                rsum += pp;
            }
#pragma unroll
            for (int off = 1; off < 16; off <<= 1)
                rsum += __shfl_xor(rsum, off, 64);
            lr[u] = lr[u] * alpha + rsum;
            mr[u] = mnew;
#pragma unroll
            for (int vv = 0; vv < 4; ++vv) o[u][vv] *= alpha;
            *(float4*)&Ps[ty * 4 + u][tx * 4] =
                make_float4(s[u][0], s[u][1], s[u][2], s[u][3]);
        }
        __syncthreads();

#pragma unroll
        for (int kk4 = 0; kk4 < 64; kk4 += 4) {
            float a[4][4];
#pragma unroll
            for (int u = 0; u < 4; ++u)
                *(float4*)a[u] = *(const float4*)&Ps[ty * 4 + u][kk4];
#pragma unroll
            for (int e = 0; e < 4; ++e) {
                float4 b4 = *(const float4*)&Vs[kk4 + e][tx * 4];
                const float b[4] = {b4.x, b4.y, b4.z, b4.w};
#pragma unroll
                for (int u = 0; u < 4; ++u)
#pragma unroll
                    for (int vv = 0; vv < 4; ++vv)
                        o[u][vv] = fmaf(a[u][e], b[vv], o[u][vv]);
            }
        }
    }

    const int bb = z >> 4, h = z & 15;
#pragma unroll
    for (int u = 0; u < 4; ++u) {
        const int ig = q0 + ty * 4 + u;
        const float inv = 1.f / lr[u];
        ushort4 r;
        r.x = f2b(o[u][0] * inv); r.y = f2b(o[u][1] * inv);
        r.z = f2b(o[u][2] * inv); r.w = f2b(o[u][3] * inv);
        *(ushort4*)(ao + (size_t)(ig * BATCH + bb) * DM + h * DHEAD + tx * 4) = r;
    }
}

// ---------------------------------------------------------------------------
extern "C" void kernel_launch(void* const* d_in, const int* in_sizes, int n_in,
                              void* d_out, int out_size, void* d_ws, size_t ws_size,
                              hipStream_t stream)
{
    const float* x    = (const float*)d_in[0];
    const float* beta = (const float*)d_in[1];
    const float* Wq   = (const float*)d_in[2];
    const float* bq   = (const float*)d_in[3];
    const float* Wk   = (const float*)d_in[4];
    const float* bk   = (const float*)d_in[5];
    const float* Wv   = (const float*)d_in[6];
    const float* bv   = (const float*)d_in[7];
    const float* Wo   = (const float*)d_in[8];
    const float* bo   = (const float*)d_in[9];
    float* out = (float*)d_out;

    unsigned short* w = (unsigned short*)d_ws;
    const size_t seg = (size_t)MROWS * DM;      // 4M elems
    unsigned short* qb  = w;
    unsigned short* kbf = w + seg;
    unsigned short* vb  = w + 2 * seg;
    unsigned short* ab  = w + 3 * seg;
    unsigned short* xb  = w + 4 * seg;
    unsigned short* wtq = w + 5 * seg;
    unsigned short* wtk = wtq + (size_t)DM * DM;
    unsigned short* wtv = wtk + (size_t)DM * DM;
    unsigned short* wto = wtv + (size_t)DM * DM;

    cvtx<<<4096, 256, 0, stream>>>(x, xb);
    dim3 tg(32, 32);
    twcvt<<<tg, 256, 0, stream>>>(Wq, wtq);
    twcvt<<<tg, 256, 0, stream>>>(Wk, wtk);
    twcvt<<<tg, 256, 0, stream>>>(Wv, wtv);
    twcvt<<<tg, 256, 0, stream>>>(Wo, wto);

    dim3 gg(DM / 64, MROWS / 128);
    gemm_mfma<<<gg, 256, 0, stream>>>(xb, wtq, bq, beta, nullptr, qb,  1);
    gemm_mfma<<<gg, 256, 0, stream>>>(xb, wtk, bk, beta, nullptr, kbf, 2);
    gemm_mfma<<<gg, 256, 0, stream>>>(xb, wtv, bv, beta, nullptr, vb,  2);

    attn_tile<<<dim3(S_LEN / TQ, BATCH * NHEAD), 256, 0, stream>>>(qb, kbf, vb, ab);

    gemm_mfma<<<gg, 256, 0, stream>>>(ab, wto, bo, beta, out, nullptr, 0);
}

// Round 4
// 206.202 us; speedup vs baseline: 6.8238x; 1.4932x over previous
//
#include <hip/hip_runtime.h>
#include <math.h>

#define S_LEN  2048
#define BATCH  2
#define DM     1024
#define NHEAD  16
#define DHEAD  64
#define WIN    256
#define MROWS  4096

#define KP   72     // bf16 LDS row stride for K/V tiles (64+8: 2-way-free banks)
#define PPAD 68     // f32 LDS row stride for P

typedef __attribute__((ext_vector_type(8))) short bf16x8;
typedef __attribute__((ext_vector_type(4))) float f32x4;

__device__ __forceinline__ float b2f(unsigned short u) {
    union { unsigned int i; float f; } x; x.i = ((unsigned int)u) << 16; return x.f;
}
__device__ __forceinline__ unsigned short f2b(float f) {   // RNE
    unsigned int u = __float_as_uint(f);
    return (unsigned short)((u + 0x7fffu + ((u >> 16) & 1u)) >> 16);
}
__device__ __forceinline__ void gld16(const void* g, void* l) {
    __builtin_amdgcn_global_load_lds(
        (const __attribute__((address_space(1))) void*)g,
        (__attribute__((address_space(3))) void*)l, 16, 0, 0);
}
__device__ __forceinline__ bf16x8 pack8(float4 a, float4 b) {
    bf16x8 r;
    r[0] = (short)f2b(a.x); r[1] = (short)f2b(a.y);
    r[2] = (short)f2b(a.z); r[3] = (short)f2b(a.w);
    r[4] = (short)f2b(b.x); r[5] = (short)f2b(b.y);
    r[6] = (short)f2b(b.z); r[7] = (short)f2b(b.w);
    return r;
}

// ---------------------------------------------------------------------------
// fp32 -> bf16 convert (x)
// ---------------------------------------------------------------------------
__global__ __launch_bounds__(256)
void cvtx(const float* __restrict__ x, unsigned short* __restrict__ xb)
{
    const int i = (blockIdx.x * 256 + threadIdx.x) * 4;
    float4 f = *(const float4*)(x + i);
    ushort4 o; o.x = f2b(f.x); o.y = f2b(f.y); o.z = f2b(f.z); o.w = f2b(f.w);
    *(ushort4*)(xb + i) = o;
}

// ---------------------------------------------------------------------------
// W (K x N fp32) -> W^T (N x K bf16)
// ---------------------------------------------------------------------------
__global__ __launch_bounds__(256)
void twcvt(const float* __restrict__ W, unsigned short* __restrict__ WT)
{
    __shared__ float t32[32][33];
    const int bx = blockIdx.x * 32;
    const int by = blockIdx.y * 32;
    const int c  = threadIdx.x & 31;
    const int r0 = threadIdx.x >> 5;
#pragma unroll
    for (int p = 0; p < 4; ++p)
        t32[r0 + 8 * p][c] = W[(size_t)(by + r0 + 8 * p) * DM + bx + c];
    __syncthreads();
#pragma unroll
    for (int p = 0; p < 4; ++p)
        WT[(size_t)(bx + r0 + 8 * p) * DM + by + c] = f2b(t32[c][r0 + 8 * p]);
}

// ---------------------------------------------------------------------------
// bf16 MFMA GEMM, tile 128x64, BK=32, 4 waves (2x2 of 64x32).
// D[row][col] = sum_k A[row][k] * BT[col][k]   (both operands K-major)
// mode 0: fp32 +bias -> Cf                  (A=ab,  BT=WoT, 4096x1024)
// mode 1: q scale+scatter bf16 (z,s,dh)     (A=xb,  BT=WqT)
// mode 2: k scatter bf16 (z,s,dh)           (A=xb,  BT=WkT)
// mode 3: v^T: rows are W-cols, cols are x-rows -> v_t[z][dh][s]
//                                           (A=WvT, BT=xb, 1024x4096)
// ---------------------------------------------------------------------------
__global__ __launch_bounds__(256, 2)
void gemm_mfma(const unsigned short* __restrict__ A,
               const unsigned short* __restrict__ BT,
               const float* __restrict__ bias,
               const float* __restrict__ beta,
               float* __restrict__ Cf,
               unsigned short* __restrict__ Cb,
               int mode)
{
    __shared__ unsigned short As[128 * 32];
    __shared__ unsigned short Bs[64 * 32];

    const int t  = threadIdx.x;
    const int wv = t >> 6, ln = t & 63;
    const int rowBase = blockIdx.y * 128;
    const int colBase = blockIdx.x * 64;

    const int lr = ln >> 2;
    const int lk = (ln & 3) * 8;
    const int m16 = ln & 15;
    const int q8  = (ln >> 4) * 8;
    const int wr = wv >> 1, wc = wv & 1;

    const unsigned short* ga = A  + (size_t)(rowBase + wv * 32 + lr) * DM + lk;
    const unsigned short* gb = BT + (size_t)(colBase + wv * 16 + lr) * DM + lk;
    unsigned short* la0 = As + wv * 1024;
    unsigned short* la1 = la0 + 512;
    unsigned short* lb  = Bs + wv * 512;

    f32x4 acc[4][2];
#pragma unroll
    for (int u = 0; u < 4; ++u)
#pragma unroll
        for (int v = 0; v < 2; ++v)
            acc[u][v] = (f32x4){0.f, 0.f, 0.f, 0.f};

    for (int kb = 0; kb < DM; kb += 32) {
        gld16(ga + kb, la0);
        gld16(ga + 16 * DM + kb, la1);
        gld16(gb + kb, lb);
        __syncthreads();

        bf16x8 af[4], bfr[2];
#pragma unroll
        for (int u = 0; u < 4; ++u)
            af[u] = *(const bf16x8*)&As[(wr * 64 + u * 16 + m16) * 32 + q8];
#pragma unroll
        for (int v = 0; v < 2; ++v)
            bfr[v] = *(const bf16x8*)&Bs[(wc * 32 + v * 16 + m16) * 32 + q8];
#pragma unroll
        for (int u = 0; u < 4; ++u)
#pragma unroll
            for (int v = 0; v < 2; ++v)
                acc[u][v] = __builtin_amdgcn_mfma_f32_16x16x32_bf16(
                    af[u], bfr[v], acc[u][v], 0, 0, 0);
        __syncthreads();
    }

    const int roww = rowBase + wr * 64;
    const int colw = colBase + wc * 32;
    const int q4 = (ln >> 4) * 4;
    if (mode == 0) {
#pragma unroll
        for (int u = 0; u < 4; ++u)
#pragma unroll
            for (int v = 0; v < 2; ++v) {
                const int col = colw + v * 16 + m16;
                const float bi = bias[col];
#pragma unroll
                for (int r = 0; r < 4; ++r) {
                    const int row = roww + u * 16 + q4 + r;
                    Cf[(size_t)row * DM + col] = acc[u][v][r] + bi;
                }
            }
    } else if (mode == 3) {
#pragma unroll
        for (int u = 0; u < 4; ++u)
#pragma unroll
            for (int v = 0; v < 2; ++v) {
                const int col = colw + v * 16 + m16;     // x row
                const int s = col >> 1, bb = col & 1;
#pragma unroll
                for (int r = 0; r < 4; ++r) {
                    const int row = roww + u * 16 + q4 + r;  // W col
                    const int hh = row >> 6, dh = row & 63;
                    const int z  = bb * NHEAD + hh;
                    Cb[((size_t)z * DHEAD + dh) * S_LEN + s] =
                        f2b(acc[u][v][r] + bias[row]);
                }
            }
    } else {
        const int h = colBase >> 6;
        const float scale = (mode == 1) ? 0.125f * __expf(-beta[h]) : 1.0f;
#pragma unroll
        for (int u = 0; u < 4; ++u)
#pragma unroll
            for (int v = 0; v < 2; ++v) {
                const int col = colw + v * 16 + m16;
                const int dh  = col & 63;
                const float bi = bias[col];
#pragma unroll
                for (int r = 0; r < 4; ++r) {
                    const int row = roww + u * 16 + q4 + r;
                    const int s = row >> 1, bb = row & 1;
                    const int z = bb * NHEAD + h;
                    Cb[((size_t)z * S_LEN + s) * DHEAD + dh] =
                        f2b((acc[u][v][r] + bi) * scale);
                }
            }
    }
}

// ---------------------------------------------------------------------------
// MFMA flash attention, windowed causal + sink.
// Block = 256 thr = 4 waves; wave w owns query rows q0+16w .. +15 of one z.
// 5 key chunks of 64. Q frags from global (held in regs). K staged bf16
// key-major; V arrives pre-transposed (z,dh,s) and stages bf16 dh-major.
// S in MFMA C-layout -> mask + online softmax (m0=0,l0=1 absorbs sink) ->
// P via f32 LDS round-trip -> PV MFMA. Output ao row-major bf16.
// ---------------------------------------------------------------------------
__global__ __launch_bounds__(256, 4)
void attn_mfma(const unsigned short* __restrict__ q,
               const unsigned short* __restrict__ k,
               const unsigned short* __restrict__ vt,
               unsigned short* __restrict__ ao)
{
    __shared__ unsigned short Ks[64 * KP];   // [key][d]
    __shared__ unsigned short Vs[64 * KP];   // [dh][key]
    __shared__ float Ps[64][PPAD];           // [wave*16 + qrow][key]

    const int t   = threadIdx.x;
    const int wv  = t >> 6, ln = t & 63;
    const int m16 = ln & 15, g = ln >> 4;
    const int z   = blockIdx.y;
    const int q0  = blockIdx.x * 64;
    const size_t zbase = (size_t)z * S_LEN * DHEAD;

    // Q A-frags: A[m=m16][kk = h*32 + g*8 + j], reused across all chunks
    const unsigned short* qrow = q + zbase + (size_t)(q0 + wv * 16 + m16) * DHEAD;
    bf16x8 qf0 = *(const bf16x8*)(qrow + g * 8);
    bf16x8 qf1 = *(const bf16x8*)(qrow + 32 + g * 8);

    f32x4 oacc[4];
#pragma unroll
    for (int v4 = 0; v4 < 4; ++v4) oacc[v4] = (f32x4){0.f, 0.f, 0.f, 0.f};
    float mr[4], lr[4];
#pragma unroll
    for (int r = 0; r < 4; ++r) { mr[r] = 0.f; lr[r] = 1.f; }  // sink

    for (int c = 0; c < 5; ++c) {
        const int kb = q0 - 256 + c * 64;
        if (kb < 0) continue;              // kb is a multiple of 64
        __syncthreads();                   // prev chunk's K/V reads done

        // stage K [64][64] and V^T [64][64], b128 copies
#pragma unroll
        for (int i = 0; i < 2; ++i) {
            const int id  = t + 256 * i;
            const int row = id >> 3;
            const int co  = (id & 7) * 8;
            *(bf16x8*)&Ks[row * KP + co] =
                *(const bf16x8*)(k + zbase + (size_t)(kb + row) * DHEAD + co);
            *(bf16x8*)&Vs[row * KP + co] =
                *(const bf16x8*)(vt + ((size_t)z * DHEAD + row) * S_LEN + kb + co);
        }
        __syncthreads();

        // S = Q K^T : rows = queries (16), cols = keys (64)
        f32x4 sacc[4];
#pragma unroll
        for (int v4 = 0; v4 < 4; ++v4) {
            sacc[v4] = (f32x4){0.f, 0.f, 0.f, 0.f};
            bf16x8 kf0 = *(const bf16x8*)&Ks[(v4 * 16 + m16) * KP + g * 8];
            sacc[v4] = __builtin_amdgcn_mfma_f32_16x16x32_bf16(qf0, kf0, sacc[v4], 0, 0, 0);
            bf16x8 kf1 = *(const bf16x8*)&Ks[(v4 * 16 + m16) * KP + 32 + g * 8];
            sacc[v4] = __builtin_amdgcn_mfma_f32_16x16x32_bf16(qf1, kf1, sacc[v4], 0, 0, 0);
        }

        // mask + online softmax (C layout: row = g*4+r, col = v4*16+m16)
        const bool mhi = (c == 4), mlo = (c == 0);
#pragma unroll
        for (int r = 0; r < 4; ++r) {
            const int ig = q0 + wv * 16 + g * 4 + r;
            float sv[4];
            float smax = -1e30f;
#pragma unroll
            for (int v4 = 0; v4 < 4; ++v4) {
                const int jg = kb + v4 * 16 + m16;
                float x = sacc[v4][r];
                const bool valid = (!mhi || jg <= ig) && (!mlo || jg >= ig - (WIN - 1));
                x = valid ? x : -1e30f;
                sv[v4] = x;
                smax = fmaxf(smax, x);
            }
#pragma unroll
            for (int off = 1; off < 16; off <<= 1)
                smax = fmaxf(smax, __shfl_xor(smax, off, 64));
            const float mnew  = fmaxf(mr[r], smax);
            const float alpha = __expf(mr[r] - mnew);
            float rsum = 0.f;
#pragma unroll
            for (int v4 = 0; v4 < 4; ++v4) {
                const float pp = __expf(sv[v4] - mnew);   // masked -> 0 (underflow)
                Ps[wv * 16 + g * 4 + r][v4 * 16 + m16] = pp;
                rsum += pp;
            }
#pragma unroll
            for (int off = 1; off < 16; off <<= 1)
                rsum += __shfl_xor(rsum, off, 64);
            lr[r] = lr[r] * alpha + rsum;
            mr[r] = mnew;
#pragma unroll
            for (int v4 = 0; v4 < 4; ++v4) oacc[v4][r] *= alpha;
        }
        __syncthreads();   // P write -> read (also keeps waves in step)

        // O += P V : A = P[m=query][k=key], B = Vs[n=dh][k=key]
        const float* prow = &Ps[wv * 16 + m16][0];
        bf16x8 pf0 = pack8(*(const float4*)(prow + g * 8),
                           *(const float4*)(prow + g * 8 + 4));
        bf16x8 pf1 = pack8(*(const float4*)(prow + 32 + g * 8),
                           *(const float4*)(prow + 32 + g * 8 + 4));
#pragma unroll
        for (int v4 = 0; v4 < 4; ++v4) {
            bf16x8 vf0 = *(const bf16x8*)&Vs[(v4 * 16 + m16) * KP + g * 8];
            oacc[v4] = __builtin_amdgcn_mfma_f32_16x16x32_bf16(pf0, vf0, oacc[v4], 0, 0, 0);
            bf16x8 vf1 = *(const bf16x8*)&Vs[(v4 * 16 + m16) * KP + 32 + g * 8];
            oacc[v4] = __builtin_amdgcn_mfma_f32_16x16x32_bf16(pf1, vf1, oacc[v4], 0, 0, 0);
        }
    }

    // epilogue: normalize rows, store bf16 to (s*B+b, h*64+dh)
    const int bb = z >> 4, h = z & 15;
#pragma unroll
    for (int r = 0; r < 4; ++r) {
        const int ig  = q0 + wv * 16 + g * 4 + r;
        const float inv = 1.f / lr[r];
#pragma unroll
        for (int v4 = 0; v4 < 4; ++v4)
            ao[(size_t)(ig * BATCH + bb) * DM + h * DHEAD + v4 * 16 + m16] =
                f2b(oacc[v4][r] * inv);
    }
}

// ---------------------------------------------------------------------------
extern "C" void kernel_launch(void* const* d_in, const int* in_sizes, int n_in,
                              void* d_out, int out_size, void* d_ws, size_t ws_size,
                              hipStream_t stream)
{
    const float* x    = (const float*)d_in[0];
    const float* beta = (const float*)d_in[1];
    const float* Wq   = (const float*)d_in[2];
    const float* bq   = (const float*)d_in[3];
    const float* Wk   = (const float*)d_in[4];
    const float* bk   = (const float*)d_in[5];
    const float* Wv   = (const float*)d_in[6];
    const float* bv   = (const float*)d_in[7];
    const float* Wo   = (const float*)d_in[8];
    const float* bo   = (const float*)d_in[9];
    float* out = (float*)d_out;

    unsigned short* w = (unsigned short*)d_ws;
    const size_t seg = (size_t)MROWS * DM;      // 4M elems
    unsigned short* qb  = w;
    unsigned short* kbf = w + seg;
    unsigned short* vtb = w + 2 * seg;          // (z, dh, s)
    unsigned short* ab  = w + 3 * seg;
    unsigned short* xb  = w + 4 * seg;
    unsigned short* wtq = w + 5 * seg;
    unsigned short* wtk = wtq + (size_t)DM * DM;
    unsigned short* wtv = wtk + (size_t)DM * DM;
    unsigned short* wto = wtv + (size_t)DM * DM;

    cvtx<<<4096, 256, 0, stream>>>(x, xb);
    dim3 tg(32, 32);
    twcvt<<<tg, 256, 0, stream>>>(Wq, wtq);
    twcvt<<<tg, 256, 0, stream>>>(Wk, wtk);
    twcvt<<<tg, 256, 0, stream>>>(Wv, wtv);
    twcvt<<<tg, 256, 0, stream>>>(Wo, wto);

    dim3 gg(DM / 64, MROWS / 128);
    gemm_mfma<<<gg, 256, 0, stream>>>(xb, wtq, bq, beta, nullptr, qb,  1);
    gemm_mfma<<<gg, 256, 0, stream>>>(xb, wtk, bk, beta, nullptr, kbf, 2);
    dim3 gv(MROWS / 64, DM / 128);
    gemm_mfma<<<gv, 256, 0, stream>>>(wtv, xb, bv, beta, nullptr, vtb, 3);

    attn_mfma<<<dim3(S_LEN / 64, BATCH * NHEAD), 256, 0, stream>>>(qb, kbf, vtb, ab);

    gemm_mfma<<<gg, 256, 0, stream>>>(ab, wto, bo, beta, out, nullptr, 0);
}

// Round 5
// 194.254 us; speedup vs baseline: 7.2436x; 1.0615x over previous
//
#include <hip/hip_runtime.h>
#include <math.h>

#define S_LEN  2048
#define BATCH  2
#define DM     1024
#define NHEAD  16
#define DHEAD  64
#define WIN    256
#define MROWS  4096

#define KP   72     // bf16 LDS row stride for attn K/V tiles
#define PPAD 68     // f32 LDS row stride for attn P

typedef __attribute__((ext_vector_type(8))) short bf16x8;
typedef __attribute__((ext_vector_type(4))) float f32x4;

__device__ __forceinline__ unsigned short f2b(float f) {   // RNE
    unsigned int u = __float_as_uint(f);
    return (unsigned short)((u + 0x7fffu + ((u >> 16) & 1u)) >> 16);
}
__device__ __forceinline__ void gld16(const void* g, void* l) {
    __builtin_amdgcn_global_load_lds(
        (const __attribute__((address_space(1))) void*)g,
        (__attribute__((address_space(3))) void*)l, 16, 0, 0);
}
__device__ __forceinline__ bf16x8 pack8(float4 a, float4 b) {
    bf16x8 r;
    r[0] = (short)f2b(a.x); r[1] = (short)f2b(a.y);
    r[2] = (short)f2b(a.z); r[3] = (short)f2b(a.w);
    r[4] = (short)f2b(b.x); r[5] = (short)f2b(b.y);
    r[6] = (short)f2b(b.z); r[7] = (short)f2b(b.w);
    return r;
}

// ---------------------------------------------------------------------------
// fp32 -> bf16 convert (x)
// ---------------------------------------------------------------------------
__global__ __launch_bounds__(256)
void cvtx(const float* __restrict__ x, unsigned short* __restrict__ xb)
{
    const int i = (blockIdx.x * 256 + threadIdx.x) * 4;
    float4 f = *(const float4*)(x + i);
    ushort4 o; o.x = f2b(f.x); o.y = f2b(f.y); o.z = f2b(f.z); o.w = f2b(f.w);
    *(ushort4*)(xb + i) = o;
}

// ---------------------------------------------------------------------------
// 4x fused: W (K x N fp32) -> W^T (N x K bf16); blockIdx.z selects matrix
// ---------------------------------------------------------------------------
__global__ __launch_bounds__(256)
void twcvt4(const float* __restrict__ W0, const float* __restrict__ W1,
            const float* __restrict__ W2, const float* __restrict__ W3,
            unsigned short* __restrict__ T0, unsigned short* __restrict__ T1,
            unsigned short* __restrict__ T2, unsigned short* __restrict__ T3)
{
    const int zz = blockIdx.z;
    const float* W = (zz == 0) ? W0 : (zz == 1) ? W1 : (zz == 2) ? W2 : W3;
    unsigned short* WT = (zz == 0) ? T0 : (zz == 1) ? T1 : (zz == 2) ? T2 : T3;

    __shared__ float t32[32][33];
    const int bx = blockIdx.x * 32;
    const int by = blockIdx.y * 32;
    const int c  = threadIdx.x & 31;
    const int r0 = threadIdx.x >> 5;
#pragma unroll
    for (int p = 0; p < 4; ++p)
        t32[r0 + 8 * p][c] = W[(size_t)(by + r0 + 8 * p) * DM + bx + c];
    __syncthreads();
#pragma unroll
    for (int p = 0; p < 4; ++p)
        WT[(size_t)(bx + r0 + 8 * p) * DM + by + c] = f2b(t32[c][r0 + 8 * p]);
}

// ---------------------------------------------------------------------------
// bf16 MFMA GEMM, m97-style 128x128 tile, BK=32, 4 waves (2x2 of 64x64),
// 16 MFMA + 8 ds_read_b128 per wave-kstep. XOR k-group swizzle (applied on
// the gld16 SOURCE address; LDS dest stays wave-uniform-base + lane*16)
// reduces fragment-read bank conflicts 8-way -> 4-way.
//   D[row][col] = sum_k A[row][k] * BT[col][k]
// mode 0: fp32 +bias -> Cf            (A=ab,  BT=WoT, M=4096 N=1024)
// mode 1: fused QK scatter bf16       (A=xb,  BT=WqT|WkT, M=4096 N=2048)
//         col<1024 -> q (scale 0.125*exp(-beta[h])), else k; z=(row&1)*16+h
// mode 3: v^T scatter bf16 (z,dh,s)   (A=WvT, BT=xb,  M=1024 N=4096)
// ---------------------------------------------------------------------------
__global__ __launch_bounds__(256)
void gemm_mfma(const unsigned short* __restrict__ A,
               const unsigned short* __restrict__ BT,
               const float* __restrict__ bias,
               const float* __restrict__ bias2,
               const float* __restrict__ beta,
               float* __restrict__ Cf,
               unsigned short* __restrict__ Cb,
               int mode)
{
    __shared__ unsigned short As[128 * 32];   // 8 KB
    __shared__ unsigned short Bs[128 * 32];   // 8 KB

    const int t  = threadIdx.x;
    const int wv = t >> 6, ln = t & 63;
    const int rowBase = blockIdx.y * 128;
    const int colBase = blockIdx.x * 128;

    const int m16 = ln & 15, g = ln >> 4;
    const int wr = wv >> 1, wc = wv & 1;
    const int swz = m16 & 3;

    // staging: lane ln covers LDS slot (row = wv*16 + ln>>2, j = ln&3);
    // content = k-group j ^ (row&3)  (XOR swizzle)
    const int lr = ln >> 2;
    const int lq = (ln & 3) ^ (lr & 3);
    const unsigned short* ga = A  + (size_t)(rowBase + wv * 16 + lr) * DM + lq * 8;
    const unsigned short* gb = BT + (size_t)(colBase + wv * 16 + lr) * DM + lq * 8;
    unsigned short* la0 = As + wv * 512;
    unsigned short* la1 = la0 + 2048;         // rows 64..127
    unsigned short* lb0 = Bs + wv * 512;
    unsigned short* lb1 = lb0 + 2048;

    f32x4 acc[4][4];
#pragma unroll
    for (int u = 0; u < 4; ++u)
#pragma unroll
        for (int v = 0; v < 4; ++v)
            acc[u][v] = (f32x4){0.f, 0.f, 0.f, 0.f};

    for (int kb = 0; kb < DM; kb += 32) {
        gld16(ga + kb, la0);
        gld16(ga + (size_t)64 * DM + kb, la1);
        gld16(gb + kb, lb0);
        gld16(gb + (size_t)64 * DM + kb, lb1);
        __syncthreads();

        bf16x8 af[4], bfr[4];
#pragma unroll
        for (int u = 0; u < 4; ++u)
            af[u] = *(const bf16x8*)&As[(wr * 64 + u * 16 + m16) * 32 + ((g ^ swz) * 8)];
#pragma unroll
        for (int v = 0; v < 4; ++v)
            bfr[v] = *(const bf16x8*)&Bs[(wc * 64 + v * 16 + m16) * 32 + ((g ^ swz) * 8)];
#pragma unroll
        for (int u = 0; u < 4; ++u)
#pragma unroll
            for (int v = 0; v < 4; ++v)
                acc[u][v] = __builtin_amdgcn_mfma_f32_16x16x32_bf16(
                    af[u], bfr[v], acc[u][v], 0, 0, 0);
        __syncthreads();
    }

    // C layout per 16x16 frag: col = m16, row = g*4 + r
    const int q4 = g * 4;
    if (mode == 0) {
#pragma unroll
        for (int v = 0; v < 4; ++v) {
            const int col = colBase + wc * 64 + v * 16 + m16;
            const float bi = bias[col];
#pragma unroll
            for (int u = 0; u < 4; ++u)
#pragma unroll
                for (int r = 0; r < 4; ++r) {
                    const int row = rowBase + wr * 64 + u * 16 + q4 + r;
                    Cf[(size_t)row * DM + col] = acc[u][v][r] + bi;
                }
        }
    } else if (mode == 1) {
#pragma unroll
        for (int v = 0; v < 4; ++v) {
            const int col  = colBase + wc * 64 + v * 16 + m16;
            const bool isq = (col < DM);
            const int h    = (col >> 6) & (NHEAD - 1);
            const int dh   = col & 63;
            const float bi = isq ? bias[col] : bias2[col - DM];
            const float sc = isq ? 0.125f * __expf(-beta[h]) : 1.0f;
            unsigned short* base = Cb + (isq ? 0 : (size_t)MROWS * DM);
#pragma unroll
            for (int u = 0; u < 4; ++u)
#pragma unroll
                for (int r = 0; r < 4; ++r) {
                    const int row = rowBase + wr * 64 + u * 16 + q4 + r;
                    const int s = row >> 1, bb = row & 1;
                    const int z = bb * NHEAD + h;
                    base[((size_t)z * S_LEN + s) * DHEAD + dh] =
                        f2b((acc[u][v][r] + bi) * sc);
                }
        }
    } else {   // mode 3: v^T
#pragma unroll
        for (int u = 0; u < 4; ++u)
#pragma unroll
            for (int r = 0; r < 4; ++r) {
                const int row = rowBase + wr * 64 + u * 16 + q4 + r;   // W col
                const int hh = row >> 6, dh = row & 63;
                const float bi = bias[row];
#pragma unroll
                for (int v = 0; v < 4; ++v) {
                    const int col = colBase + wc * 64 + v * 16 + m16;  // x row
                    const int s = col >> 1, bb = col & 1;
                    Cb[((size_t)(bb * NHEAD + hh) * DHEAD + dh) * S_LEN + s] =
                        f2b(acc[u][v][r] + bi);
                }
            }
    }
}

// ---------------------------------------------------------------------------
// MFMA flash attention, windowed causal + sink (unchanged from R4).
// ---------------------------------------------------------------------------
__global__ __launch_bounds__(256, 4)
void attn_mfma(const unsigned short* __restrict__ q,
               const unsigned short* __restrict__ k,
               const unsigned short* __restrict__ vt,
               unsigned short* __restrict__ ao)
{
    __shared__ unsigned short Ks[64 * KP];   // [key][d]
    __shared__ unsigned short Vs[64 * KP];   // [dh][key]
    __shared__ float Ps[64][PPAD];           // [wave*16 + qrow][key]

    const int t   = threadIdx.x;
    const int wv  = t >> 6, ln = t & 63;
    const int m16 = ln & 15, g = ln >> 4;
    const int z   = blockIdx.y;
    const int q0  = blockIdx.x * 64;
    const size_t zbase = (size_t)z * S_LEN * DHEAD;

    const unsigned short* qrow = q + zbase + (size_t)(q0 + wv * 16 + m16) * DHEAD;
    bf16x8 qf0 = *(const bf16x8*)(qrow + g * 8);
    bf16x8 qf1 = *(const bf16x8*)(qrow + 32 + g * 8);

    f32x4 oacc[4];
#pragma unroll
    for (int v4 = 0; v4 < 4; ++v4) oacc[v4] = (f32x4){0.f, 0.f, 0.f, 0.f};
    float mr[4], lr[4];
#pragma unroll
    for (int r = 0; r < 4; ++r) { mr[r] = 0.f; lr[r] = 1.f; }  // sink

    for (int c = 0; c < 5; ++c) {
        const int kb = q0 - 256 + c * 64;
        if (kb < 0) continue;
        __syncthreads();

#pragma unroll
        for (int i = 0; i < 2; ++i) {
            const int id  = t + 256 * i;
            const int row = id >> 3;
            const int co  = (id & 7) * 8;
            *(bf16x8*)&Ks[row * KP + co] =
                *(const bf16x8*)(k + zbase + (size_t)(kb + row) * DHEAD + co);
            *(bf16x8*)&Vs[row * KP + co] =
                *(const bf16x8*)(vt + ((size_t)z * DHEAD + row) * S_LEN + kb + co);
        }
        __syncthreads();

        f32x4 sacc[4];
#pragma unroll
        for (int v4 = 0; v4 < 4; ++v4) {
            sacc[v4] = (f32x4){0.f, 0.f, 0.f, 0.f};
            bf16x8 kf0 = *(const bf16x8*)&Ks[(v4 * 16 + m16) * KP + g * 8];
            sacc[v4] = __builtin_amdgcn_mfma_f32_16x16x32_bf16(qf0, kf0, sacc[v4], 0, 0, 0);
            bf16x8 kf1 = *(const bf16x8*)&Ks[(v4 * 16 + m16) * KP + 32 + g * 8];
            sacc[v4] = __builtin_amdgcn_mfma_f32_16x16x32_bf16(qf1, kf1, sacc[v4], 0, 0, 0);
        }

        const bool mhi = (c == 4), mlo = (c == 0);
#pragma unroll
        for (int r = 0; r < 4; ++r) {
            const int ig = q0 + wv * 16 + g * 4 + r;
            float sv[4];
            float smax = -1e30f;
#pragma unroll
            for (int v4 = 0; v4 < 4; ++v4) {
                const int jg = kb + v4 * 16 + m16;
                float x = sacc[v4][r];
                const bool valid = (!mhi || jg <= ig) && (!mlo || jg >= ig - (WIN - 1));
                x = valid ? x : -1e30f;
                sv[v4] = x;
                smax = fmaxf(smax, x);
            }
#pragma unroll
            for (int off = 1; off < 16; off <<= 1)
                smax = fmaxf(smax, __shfl_xor(smax, off, 64));
            const float mnew  = fmaxf(mr[r], smax);
            const float alpha = __expf(mr[r] - mnew);
            float rsum = 0.f;
#pragma unroll
            for (int v4 = 0; v4 < 4; ++v4) {
                const float pp = __expf(sv[v4] - mnew);
                Ps[wv * 16 + g * 4 + r][v4 * 16 + m16] = pp;
                rsum += pp;
            }
#pragma unroll
            for (int off = 1; off < 16; off <<= 1)
                rsum += __shfl_xor(rsum, off, 64);
            lr[r] = lr[r] * alpha + rsum;
            mr[r] = mnew;
#pragma unroll
            for (int v4 = 0; v4 < 4; ++v4) oacc[v4][r] *= alpha;
        }
        __syncthreads();

        const float* prow = &Ps[wv * 16 + m16][0];
        bf16x8 pf0 = pack8(*(const float4*)(prow + g * 8),
                           *(const float4*)(prow + g * 8 + 4));
        bf16x8 pf1 = pack8(*(const float4*)(prow + 32 + g * 8),
                           *(const float4*)(prow + 32 + g * 8 + 4));
#pragma unroll
        for (int v4 = 0; v4 < 4; ++v4) {
            bf16x8 vf0 = *(const bf16x8*)&Vs[(v4 * 16 + m16) * KP + g * 8];
            oacc[v4] = __builtin_amdgcn_mfma_f32_16x16x32_bf16(pf0, vf0, oacc[v4], 0, 0, 0);
            bf16x8 vf1 = *(const bf16x8*)&Vs[(v4 * 16 + m16) * KP + 32 + g * 8];
            oacc[v4] = __builtin_amdgcn_mfma_f32_16x16x32_bf16(pf1, vf1, oacc[v4], 0, 0, 0);
        }
    }

    const int bb = z >> 4, h = z & 15;
#pragma unroll
    for (int r = 0; r < 4; ++r) {
        const int ig  = q0 + wv * 16 + g * 4 + r;
        const float inv = 1.f / lr[r];
#pragma unroll
        for (int v4 = 0; v4 < 4; ++v4)
            ao[(size_t)(ig * BATCH + bb) * DM + h * DHEAD + v4 * 16 + m16] =
                f2b(oacc[v4][r] * inv);
    }
}

// ---------------------------------------------------------------------------
extern "C" void kernel_launch(void* const* d_in, const int* in_sizes, int n_in,
                              void* d_out, int out_size, void* d_ws, size_t ws_size,
                              hipStream_t stream)
{
    const float* x    = (const float*)d_in[0];
    const float* beta = (const float*)d_in[1];
    const float* Wq   = (const float*)d_in[2];
    const float* bq   = (const float*)d_in[3];
    const float* Wk   = (const float*)d_in[4];
    const float* bk   = (const float*)d_in[5];
    const float* Wv   = (const float*)d_in[6];
    const float* bv   = (const float*)d_in[7];
    const float* Wo   = (const float*)d_in[8];
    const float* bo   = (const float*)d_in[9];
    float* out = (float*)d_out;

    unsigned short* w = (unsigned short*)d_ws;
    const size_t seg = (size_t)MROWS * DM;      // 4M elems
    unsigned short* qb  = w;                    // q (z,s,dh)
    unsigned short* kbf = w + seg;              // k (z,s,dh)  -- contiguous after qb!
    unsigned short* vtb = w + 2 * seg;          // v^T (z,dh,s)
    unsigned short* ab  = w + 3 * seg;          // attn out, row-major
    unsigned short* xb  = w + 4 * seg;          // x bf16
    unsigned short* wtq = w + 5 * seg;          // WqT -- wtk contiguous after
    unsigned short* wtk = wtq + (size_t)DM * DM;
    unsigned short* wtv = wtk + (size_t)DM * DM;
    unsigned short* wto = wtv + (size_t)DM * DM;

    cvtx<<<4096, 256, 0, stream>>>(x, xb);
    twcvt4<<<dim3(32, 32, 4), 256, 0, stream>>>(Wq, Wk, Wv, Wo, wtq, wtk, wtv, wto);

    // fused Q+K projection: N=2048 (wtq|wtk contiguous), writes qb|kbf
    gemm_mfma<<<dim3(2048 / 128, MROWS / 128), 256, 0, stream>>>(
        xb, wtq, bq, bk, beta, nullptr, qb, 1);
    // v^T: swapped operands, M=1024, N=4096
    gemm_mfma<<<dim3(MROWS / 128, DM / 128), 256, 0, stream>>>(
        wtv, xb, bv, nullptr, beta, nullptr, vtb, 3);

    attn_mfma<<<dim3(S_LEN / 64, BATCH * NHEAD), 256, 0, stream>>>(qb, kbf, vtb, ab);

    // output projection
    gemm_mfma<<<dim3(DM / 128, MROWS / 128), 256, 0, stream>>>(
        ab, wto, bo, nullptr, beta, out, nullptr, 0);
}